// Round 1
// baseline (231.490 us; speedup 1.0000x reference)
//
#include <hip/hip_runtime.h>
#include <cstdint>
#include <cmath>

#define SEQ 1024
#define BATCH 8
#define NK 4

// ---------------------------------------------------------------------------
// Kernel A: factA4[b,i] = 0.7 if exists p<i with any_k rel[b,i,p,k] > 0.5 else 1.0
// (maxrel>0.5 is implied by exists_earlier, so maxrel is not needed.)
// One 256-thread block per (b,i) row; each float4 is exactly one p (K=4).
// Chunked early-exit: with uniform data the first 256-p chunk almost always hits.
// ---------------------------------------------------------------------------
__global__ __launch_bounds__(256) void krelA(const float* __restrict__ rel,
                                             float* __restrict__ factA4) {
    int row = blockIdx.x;              // b*SEQ + i
    int i = row & (SEQ - 1);
    const float4* row4 = reinterpret_cast<const float4*>(rel) + (size_t)row * SEQ;
    int tid = threadIdx.x;
    bool found = false;
    for (int base = 0; base < i; base += 256) {
        int p = base + tid;
        bool pred = false;
        if (p < i) {
            float4 v = row4[p];
            pred = (v.x > 0.5f) | (v.y > 0.5f) | (v.z > 0.5f) | (v.w > 0.5f);
        }
        if (__syncthreads_or((int)pred)) { found = true; break; }
    }
    if (tid == 0) factA4[row] = found ? 0.7f : 1.0f;
}

// ---------------------------------------------------------------------------
// Kernel B: per-position factors + precomputed activity bits.
//   mult1 (consistency MLP), factA2/factO2 (implicit-needs-nearby-explicit),
//   faf = factA2*factA4, fof = factO2,
//   flags bit0 = act if isolated (fact3=0.1), bit1 = act if not (fact3=1),
//   bit2 = act of ORIGINAL row.
// Positive factors => max commutes with scaling, so act bits are precomputable.
// ---------------------------------------------------------------------------
__global__ __launch_bounds__(256) void kfact(
    const float4* __restrict__ aL4, const float4* __restrict__ oL4,
    const int* __restrict__ exA, const int* __restrict__ exO,
    const float* __restrict__ W1, const float* __restrict__ b1,
    const float* __restrict__ W2, const float* __restrict__ b2,
    const float* __restrict__ W3, const float* __restrict__ b3,
    const float* __restrict__ factA4,
    float* __restrict__ mult1_o, float* __restrict__ faf_o,
    float* __restrict__ fof_o, int* __restrict__ flags_o) {
    int gid = blockIdx.x * 256 + threadIdx.x;   // 0..8191
    int b = gid >> 10, i = gid & (SEQ - 1);

    float4 a = aL4[gid], o = oL4[gid];
    float x[8] = {a.x, a.y, a.z, a.w, o.x, o.y, o.z, o.w};

    // MLP 8 -> 32 -> 16 -> 1, relu, relu, sigmoid (all loops fully unrolled)
    float h1[32];
#pragma unroll
    for (int j = 0; j < 32; ++j) h1[j] = b1[j];
#pragma unroll
    for (int k = 0; k < 8; ++k)
#pragma unroll
        for (int j = 0; j < 32; ++j) h1[j] = fmaf(x[k], W1[k * 32 + j], h1[j]);
#pragma unroll
    for (int j = 0; j < 32; ++j) h1[j] = fmaxf(h1[j], 0.0f);

    float h2[16];
#pragma unroll
    for (int j = 0; j < 16; ++j) h2[j] = b2[j];
#pragma unroll
    for (int k = 0; k < 32; ++k)
#pragma unroll
        for (int j = 0; j < 16; ++j) h2[j] = fmaf(h1[k], W2[k * 16 + j], h2[j]);
#pragma unroll
    for (int j = 0; j < 16; ++j) h2[j] = fmaxf(h2[j], 0.0f);

    float z = b3[0];
#pragma unroll
    for (int k = 0; k < 16; ++k) z = fmaf(h2[k], W3[k], z);
    float c = 1.0f / (1.0f + expf(-z));
    float m1 = (c < 0.5f) ? (2.0f * c) : 1.0f;

    // softmax top-2 fractions
    float ma = fmaxf(fmaxf(a.x, a.y), fmaxf(a.z, a.w));
    float ea0 = expf(a.x - ma), ea1 = expf(a.y - ma), ea2 = expf(a.z - ma), ea3 = expf(a.w - ma);
    bool impA = (ea0 + ea1) / (ea0 + ea1 + ea2 + ea3) > 0.5f;
    float mo = fmaxf(fmaxf(o.x, o.y), fmaxf(o.z, o.w));
    float eo0 = expf(o.x - mo), eo1 = expf(o.y - mo), eo2 = expf(o.z - mo), eo3 = expf(o.w - mo);
    bool impO = (eo0 + eo1) / (eo0 + eo1 + eo2 + eo3) > 0.5f;

    // window-3 any of explicit flags
    bool nearA = false, nearO = false;
#pragma unroll
    for (int d = -3; d <= 3; ++d) {
        int j = i + d;
        if (j >= 0 && j < SEQ) {
            nearA |= exA[b * SEQ + j] > 0;
            nearO |= exO[b * SEQ + j] > 0;
        }
    }
    float fA2 = (impA && !nearO) ? 0.3f : 1.0f;
    float fO2 = (impO && !nearA) ? 0.3f : 1.0f;
    float faf = fA2 * factA4[gid];   // fixed part of fa (fact3 applied later)
    float fof = fO2;

    // activity bits of the UPDATED row under fact3 = 0.1 vs 1.0
    float a01 = fmaxf(a.x, a.y) * m1, a23 = fmaxf(a.z, a.w) * m1;
    float o01 = fmaxf(o.x, o.y) * m1, o23 = fmaxf(o.z, o.w) * m1;
    bool actNon = (fmaxf(a01 * faf, a23) > 0.5f) || (fmaxf(o01 * fof, o23) > 0.5f);
    bool actIso = (fmaxf(a01 * faf * 0.1f, a23) > 0.5f) || (fmaxf(o01 * fof * 0.1f, o23) > 0.5f);
    bool actOrig = (ma > 0.5f) || (mo > 0.5f);

    mult1_o[gid] = m1;
    faf_o[gid] = faf;
    fof_o[gid] = fof;
    flags_o[gid] = (int)actIso | ((int)actNon << 1) | ((int)actOrig << 2);
}

// ---------------------------------------------------------------------------
// Kernel C: one block per batch. Pack bits via __ballot into 16x 64-bit words,
// run the 2-state boolean recurrence bit-serially in thread 0 (register-only),
// then all 256 threads apply the factors and write both outputs.
//   iso[i] = !(u[i-2] | u[i-1] | actOrig[i+1] | actOrig[i+2])
//   u[i]   = iso ? actIso[i] : actNon[i]
// ---------------------------------------------------------------------------
__global__ __launch_bounds__(256) void kapply(
    const float4* __restrict__ aL4, const float4* __restrict__ oL4,
    const float* __restrict__ mult1, const float* __restrict__ faf,
    const float* __restrict__ fof, const int* __restrict__ flags,
    float4* __restrict__ outA4, float4* __restrict__ outO4) {
    int b = blockIdx.x;
    int tid = threadIdx.x;
    int base = b * SEQ;
    __shared__ unsigned long long A64[16], N64[16], R64[16], ISO[16];

#pragma unroll
    for (int it = 0; it < 4; ++it) {
        int pos = it * 256 + tid;
        int f  = flags[base + pos];
        int f1 = (pos + 1 < SEQ) ? flags[base + pos + 1] : 0;
        int f2 = (pos + 2 < SEQ) ? flags[base + pos + 2] : 0;
        int rbit = ((f1 >> 2) | (f2 >> 2)) & 1;
        unsigned long long bA = __ballot(f & 1);
        unsigned long long bN = __ballot((f >> 1) & 1);
        unsigned long long bR = __ballot(rbit);
        int w = it * 4 + (tid >> 6);
        if ((tid & 63) == 0) { A64[w] = bA; N64[w] = bN; R64[w] = bR; }
    }
    __syncthreads();

    if (tid == 0) {
        unsigned int u1 = 0, u2 = 0;   // u[i-1], u[i-2]
        for (int w = 0; w < 16; ++w) {
            unsigned long long aw = A64[w], nw = N64[w], rw = R64[w];
            unsigned long long isoW = 0;
#pragma unroll
            for (int j = 0; j < 64; ++j) {
                unsigned int ro  = (unsigned int)(rw >> j) & 1u;
                unsigned int iso = (u1 | u2 | ro) ^ 1u;
                unsigned int ab  = (unsigned int)(aw >> j) & 1u;
                unsigned int nb  = (unsigned int)(nw >> j) & 1u;
                unsigned int u   = iso ? ab : nb;
                isoW |= (unsigned long long)iso << j;
                u2 = u1; u1 = u;
            }
            ISO[w] = isoW;
        }
    }
    __syncthreads();

#pragma unroll
    for (int it = 0; it < 4; ++it) {
        int pos = it * 256 + tid;
        int gid = base + pos;
        unsigned int iso = (unsigned int)(ISO[pos >> 6] >> (pos & 63)) & 1u;
        float f3 = iso ? 0.1f : 1.0f;
        float m  = mult1[gid];
        float fa = faf[gid] * f3;
        float fo = fof[gid] * f3;
        float4 a = aL4[gid], o = oL4[gid];
        float4 ra  = make_float4(a.x * m * fa, a.y * m * fa, a.z * m, a.w * m);
        float4 rt  = make_float4(o.x * m * fo, o.y * m * fo, o.z * m, o.w * m);
        outA4[gid] = ra;
        outO4[gid] = rt;
    }
}

extern "C" void kernel_launch(void* const* d_in, const int* in_sizes, int n_in,
                              void* d_out, int out_size, void* d_ws, size_t ws_size,
                              hipStream_t stream) {
    const float* aL  = (const float*)d_in[0];
    const float* oL  = (const float*)d_in[1];
    const float* rel = (const float*)d_in[2];
    const int*   exA = (const int*)d_in[3];
    const int*   exO = (const int*)d_in[4];
    const float* W1 = (const float*)d_in[5];
    const float* b1 = (const float*)d_in[6];
    const float* W2 = (const float*)d_in[7];
    const float* b2 = (const float*)d_in[8];
    const float* W3 = (const float*)d_in[9];
    const float* b3 = (const float*)d_in[10];

    float* ws     = (float*)d_ws;
    float* factA4 = ws;                 // 8192 floats
    float* mult1  = ws + 8192;          // 8192
    float* faf    = ws + 16384;         // 8192
    float* fof    = ws + 24576;         // 8192
    int*   flags  = (int*)(ws + 32768); // 8192 ints

    float* out = (float*)d_out;         // [cA (32768 floats) | cO (32768 floats)]

    krelA<<<BATCH * SEQ, 256, 0, stream>>>(rel, factA4);
    kfact<<<(BATCH * SEQ) / 256, 256, 0, stream>>>(
        (const float4*)aL, (const float4*)oL, exA, exO,
        W1, b1, W2, b2, W3, b3, factA4, mult1, faf, fof, flags);
    kapply<<<BATCH, 256, 0, stream>>>(
        (const float4*)aL, (const float4*)oL, mult1, faf, fof, flags,
        (float4*)out, (float4*)(out + (size_t)BATCH * SEQ * NK));
}